// Round 1
// baseline (651.425 us; speedup 1.0000x reference)
//
#include <hip/hip_runtime.h>
#include <cstdint>
#include <cstddef>

// Problem constants (fixed by reference: x (4,2048,4096) f32, weight (4096,4096) f32)
#define MDIM 8192
#define NDIM 4096
#define KDIM 4096
#define TERN_THRESH 0.1f

typedef unsigned short u16;
typedef __bf16 bf16x8 __attribute__((ext_vector_type(8)));
typedef float f32x4 __attribute__((ext_vector_type(4)));
typedef u16 u16x8 __attribute__((ext_vector_type(8)));

// ---------------------------------------------------------------- helpers ---

__device__ __forceinline__ u16 f2bf(float f) {
  // round-to-nearest-even f32 -> bf16 (inputs are finite, no NaN handling)
  unsigned u = __float_as_uint(f);
  u += 0x7FFFu + ((u >> 16) & 1u);
  return (u16)(u >> 16);
}

__device__ __forceinline__ u16 tern_bf16(float w) {
  // sign(w) * (|w| > 0.1)  as bf16 bits: +1=0x3F80, -1=0xBF80, 0=0
  return w > TERN_THRESH ? (u16)0x3F80u : (w < -TERN_THRESH ? (u16)0xBF80u : (u16)0u);
}

// async global -> LDS, 16 B per lane; LDS side is wave-uniform base + lane*16
__device__ __forceinline__ void load_lds16(const u16* g, u16* s) {
  __builtin_amdgcn_global_load_lds(
      (__attribute__((address_space(1))) void*)(void*)(g),
      (__attribute__((address_space(3))) void*)(void*)(s),
      16, 0, 0);
}

// ------------------------------------------------------- conversion kernels ---

// x f32 -> bf16, 8 elements per thread (2x float4 load, 1x 16B store)
__global__ __launch_bounds__(256) void cvt_x_kernel(const float* __restrict__ x,
                                                    u16* __restrict__ xb) {
  int i = blockIdx.x * 256 + threadIdx.x;
  const float4* x4 = (const float4*)x;
  float4 a = x4[2 * i];
  float4 b = x4[2 * i + 1];
  u16x8 o;
  o[0] = f2bf(a.x); o[1] = f2bf(a.y); o[2] = f2bf(a.z); o[3] = f2bf(a.w);
  o[4] = f2bf(b.x); o[5] = f2bf(b.y); o[6] = f2bf(b.z); o[7] = f2bf(b.w);
  ((u16x8*)xb)[i] = o;
}

// weight f32 -> ternary bf16
__global__ __launch_bounds__(256) void quant_w_kernel(const float* __restrict__ w,
                                                      u16* __restrict__ qb) {
  int i = blockIdx.x * 256 + threadIdx.x;
  const float4* w4 = (const float4*)w;
  float4 a = w4[2 * i];
  float4 b = w4[2 * i + 1];
  u16x8 o;
  o[0] = tern_bf16(a.x); o[1] = tern_bf16(a.y); o[2] = tern_bf16(a.z); o[3] = tern_bf16(a.w);
  o[4] = tern_bf16(b.x); o[5] = tern_bf16(b.y); o[6] = tern_bf16(b.z); o[7] = tern_bf16(b.w);
  ((u16x8*)qb)[i] = o;
}

// ---------------------------------------------------------------- GEMM ------
// C[M][N] = Xb[M][K] * Qb[N][K]^T + bias    (both operands bf16, C fp32)
// 128x128 block tile, BK=64, 256 threads = 4 waves in 2x2, each wave 64x64
// (4x4 grid of 16x16x32 MFMA tiles). Single LDS buffer, 2-barrier K-loop,
// staging via global_load_lds dwordx4 (contiguous, unpadded LDS — required).

__global__ __launch_bounds__(256) void gemm_tern_kernel(
    const u16* __restrict__ Xb,    // [MDIM][KDIM] bf16 bits
    const u16* __restrict__ Qb,    // [NDIM][KDIM] bf16 bits
    const float* __restrict__ bias, // [NDIM]
    float* __restrict__ C) {        // [MDIM][NDIM]
  __shared__ __attribute__((aligned(16))) u16 As[128 * 64];
  __shared__ __attribute__((aligned(16))) u16 Bs[128 * 64];

  const int tid  = threadIdx.x;
  const int lane = tid & 63;
  const int wv   = tid >> 6;
  const int wm   = wv >> 1;       // wave row (0..1)
  const int wn   = wv & 1;        // wave col (0..1)
  const int quad = lane >> 4;     // 0..3
  const int l16  = lane & 15;

  const int rowBase = blockIdx.y * 128;  // M
  const int colBase = blockIdx.x * 128;  // N

  // Staging: each tile is 128 rows x 64 k = 1024 chunks of 16 B (8 bf16).
  // Thread handles chunks c = tid + j*256 -> row = c>>3, koff = (c&7)*8.
  // LDS dest = tile_base + c*16 B: affine in lane with coeff 16 B -> legal.
  const u16* ga[4];
  const u16* gb[4];
  u16* sa[4];
  u16* sb[4];
#pragma unroll
  for (int j = 0; j < 4; ++j) {
    int c  = tid + j * 256;
    int r  = c >> 3;
    int k8 = (c & 7) * 8;
    ga[j] = Xb + (size_t)(rowBase + r) * KDIM + k8;
    gb[j] = Qb + (size_t)(colBase + r) * KDIM + k8;
    sa[j] = (u16*)As + c * 8;
    sb[j] = (u16*)Bs + c * 8;
  }

  // Fragment LDS element offsets (row stride 64 elems)
  int aoff[4], boff[4];
#pragma unroll
  for (int i = 0; i < 4; ++i) {
    aoff[i] = (wm * 64 + i * 16 + l16) * 64 + quad * 8;
    boff[i] = (wn * 64 + i * 16 + l16) * 64 + quad * 8;
  }

  f32x4 acc[4][4] = {};

  for (int kb = 0; kb < KDIM; kb += 64) {
    __syncthreads();  // previous compute done before LDS overwrite
#pragma unroll
    for (int j = 0; j < 4; ++j) {
      load_lds16(ga[j] + kb, sa[j]);
      load_lds16(gb[j] + kb, sb[j]);
    }
    __syncthreads();  // drains vmcnt -> staged data visible
#pragma unroll
    for (int kk = 0; kk < 2; ++kk) {
      bf16x8 af[4], bfr[4];
#pragma unroll
      for (int i = 0; i < 4; ++i) {
        af[i]  = *(const bf16x8*)((const u16*)As + aoff[i] + kk * 32);
        bfr[i] = *(const bf16x8*)((const u16*)Bs + boff[i] + kk * 32);
      }
#pragma unroll
      for (int i = 0; i < 4; ++i) {
#pragma unroll
        for (int j = 0; j < 4; ++j) {
          acc[i][j] = __builtin_amdgcn_mfma_f32_16x16x32_bf16(af[i], bfr[j], acc[i][j], 0, 0, 0);
        }
      }
    }
  }

  // Epilogue: C/D layout col = lane&15, row = quad*4 + reg
  float bv[4];
#pragma unroll
  for (int j = 0; j < 4; ++j) bv[j] = bias[colBase + wn * 64 + j * 16 + l16];

#pragma unroll
  for (int i = 0; i < 4; ++i) {
#pragma unroll
    for (int r = 0; r < 4; ++r) {
      int grow = rowBase + wm * 64 + i * 16 + quad * 4 + r;
      float* crow = C + (size_t)grow * NDIM + colBase + wn * 64 + l16;
#pragma unroll
      for (int j = 0; j < 4; ++j) {
        crow[j * 16] = acc[i][j][r] + bv[j];
      }
    }
  }
}

// ---------------------------------------------------------------- launch ----

extern "C" void kernel_launch(void* const* d_in, const int* in_sizes, int n_in,
                              void* d_out, int out_size, void* d_ws, size_t ws_size,
                              hipStream_t stream) {
  const float* x    = (const float*)d_in[0];
  const float* w    = (const float*)d_in[1];
  const float* bias = (const float*)d_in[2];
  float* out = (float*)d_out;

  // workspace: Xb bf16 [MDIM*KDIM] then Qb bf16 [NDIM*KDIM]  (= 100.7 MB)
  u16* xb = (u16*)d_ws;
  u16* qb = xb + (size_t)MDIM * KDIM;

  cvt_x_kernel<<<((size_t)MDIM * KDIM) / (8 * 256), 256, 0, stream>>>(x, xb);
  quant_w_kernel<<<((size_t)NDIM * KDIM) / (8 * 256), 256, 0, stream>>>(w, qb);

  dim3 grid(NDIM / 128, MDIM / 128);
  gemm_tern_kernel<<<grid, 256, 0, stream>>>(xb, qb, bias, out);
}

// Round 3
// 498.777 us; speedup vs baseline: 1.3060x; 1.3060x over previous
//
#include <hip/hip_runtime.h>
#include <cstdint>
#include <cstddef>

// Problem constants (fixed by reference: x (4,2048,4096) f32, weight (4096,4096) f32)
#define MDIM 8192
#define NDIM 4096
#define KDIM 4096
#define TERN_THRESH 0.1f

typedef unsigned short u16;
typedef __bf16 bf16x8 __attribute__((ext_vector_type(8)));
typedef float f32x4 __attribute__((ext_vector_type(4)));
typedef u16 u16x8 __attribute__((ext_vector_type(8)));

// ---------------------------------------------------------------- helpers ---

__device__ __forceinline__ u16 f2bf(float f) {
  // round-to-nearest-even f32 -> bf16 (inputs are finite, no NaN handling)
  unsigned u = __float_as_uint(f);
  u += 0x7FFFu + ((u >> 16) & 1u);
  return (u16)(u >> 16);
}

__device__ __forceinline__ u16 tern_bf16(float w) {
  // sign(w) * (|w| > 0.1)  as bf16 bits: +1=0x3F80, -1=0xBF80, 0=0
  return w > TERN_THRESH ? (u16)0x3F80u : (w < -TERN_THRESH ? (u16)0xBF80u : (u16)0u);
}

// async global -> LDS, 16 B per lane; LDS side is wave-uniform base + lane*16
__device__ __forceinline__ void load_lds16(const u16* g, u16* s) {
  __builtin_amdgcn_global_load_lds(
      (__attribute__((address_space(1))) void*)(void*)(g),
      (__attribute__((address_space(3))) void*)(void*)(s),
      16, 0, 0);
}

// ------------------------------------------------------- conversion kernel ---
// Fused: blocks [0, XBLOCKS) convert x f32->bf16; the rest ternarize weight.
// 8 elements per thread: 2x f32x4 nontemporal load (read-once; keep L3 for
// xb/qb which the GEMM re-reads), 1x 16B store. NOTE: nontemporal builtin
// needs clang ext_vector types (f32x4), NOT HIP's float4 struct.

#define XBLOCKS ((MDIM * (size_t)KDIM) / (8 * 256))   // 16384
#define WBLOCKS ((NDIM * (size_t)KDIM) / (8 * 256))   //  8192

__global__ __launch_bounds__(256) void cvt_kernel(const float* __restrict__ x,
                                                  u16* __restrict__ xb,
                                                  const float* __restrict__ w,
                                                  u16* __restrict__ qb) {
  size_t b = blockIdx.x;
  if (b < XBLOCKS) {
    size_t i = b * 256 + threadIdx.x;
    const f32x4* x4 = (const f32x4*)x;
    f32x4 a = __builtin_nontemporal_load(&x4[2 * i]);
    f32x4 c = __builtin_nontemporal_load(&x4[2 * i + 1]);
    u16x8 o;
    o[0] = f2bf(a[0]); o[1] = f2bf(a[1]); o[2] = f2bf(a[2]); o[3] = f2bf(a[3]);
    o[4] = f2bf(c[0]); o[5] = f2bf(c[1]); o[6] = f2bf(c[2]); o[7] = f2bf(c[3]);
    ((u16x8*)xb)[i] = o;
  } else {
    size_t i = (b - XBLOCKS) * 256 + threadIdx.x;
    const f32x4* w4 = (const f32x4*)w;
    f32x4 a = __builtin_nontemporal_load(&w4[2 * i]);
    f32x4 c = __builtin_nontemporal_load(&w4[2 * i + 1]);
    u16x8 o;
    o[0] = tern_bf16(a[0]); o[1] = tern_bf16(a[1]); o[2] = tern_bf16(a[2]); o[3] = tern_bf16(a[3]);
    o[4] = tern_bf16(c[0]); o[5] = tern_bf16(c[1]); o[6] = tern_bf16(c[2]); o[7] = tern_bf16(c[3]);
    ((u16x8*)qb)[i] = o;
  }
}

// ---------------------------------------------------------------- GEMM ------
// C[M][N] = Xb[M][K] * Qb[N][K]^T + bias    (both operands bf16, C fp32)
// 128x128 block tile, BK=64, 256 threads = 4 waves in 2x2, each wave 64x64
// (4x4 grid of 16x16x32 MFMA tiles). Single LDS buffer, 2-barrier K-loop,
// staging via global_load_lds dwordx4 (LDS side MUST be base + lane*16).
//
// LDS bank-conflict fix (R1/R2): XOR swizzle. LDS chunk index row*8 + (kc ^
// (row&7)) holds global chunk (row, kc). Staging keeps LDS side contiguous
// (legal for global_load_lds) and permutes the *global* k-chunk within each
// row's 128 B group (coalescing preserved). Fragment reads then hit byte
// addr row*128 + ((kchunk ^ (l16&7))*16): the 16 lanes of a quad spread over
// all 32 banks (2-way max = free) instead of 16-way on 4 banks (= the 1.0e8
// SQ_LDS_BANK_CONFLICT / 38%-of-cycles loss in R0).

__global__ __launch_bounds__(256) void gemm_tern_kernel(
    const u16* __restrict__ Xb,     // [MDIM][KDIM] bf16 bits
    const u16* __restrict__ Qb,     // [NDIM][KDIM] bf16 bits
    const float* __restrict__ bias, // [NDIM]
    float* __restrict__ C) {        // [MDIM][NDIM]
  __shared__ __attribute__((aligned(16))) u16 As[128 * 64];
  __shared__ __attribute__((aligned(16))) u16 Bs[128 * 64];

  const int tid  = threadIdx.x;
  const int lane = tid & 63;
  const int wv   = tid >> 6;
  const int wm   = wv >> 1;       // wave row (0..1)
  const int wn   = wv & 1;        // wave col (0..1)
  const int quad = lane >> 4;     // 0..3
  const int l16  = lane & 15;

  const int rowBase = blockIdx.y * 128;  // M
  const int colBase = blockIdx.x * 128;  // N

  // Staging: 128 rows x 64 k = 1024 chunks of 16 B. LDS chunk c holds global
  // (row = c>>3, kc = (c&7) ^ ((c>>3)&7)).
  const u16* ga[4];
  const u16* gb[4];
  u16* sa[4];
  u16* sb[4];
#pragma unroll
  for (int j = 0; j < 4; ++j) {
    int c  = tid + j * 256;
    int r  = c >> 3;
    int kc = (c & 7) ^ (r & 7);
    ga[j] = Xb + (size_t)(rowBase + r) * KDIM + kc * 8;
    gb[j] = Qb + (size_t)(colBase + r) * KDIM + kc * 8;
    sa[j] = (u16*)As + c * 8;
    sb[j] = (u16*)Bs + c * 8;
  }

  // Fragment LDS offsets (elements). Row base: row*64. K-offset for kchunk =
  // kk*4+quad at row with row&7 == l16&7:  ((kk*4+quad) ^ (l16&7)) * 8
  //   kk=0: koff0 = ((quad ^ s7)*8);  kk=1: chunk = quad^4 -> koff0 ^ 32.
  const int s7    = l16 & 7;
  const int koff0 = (quad ^ s7) * 8;
  int aoff[4], boff[4];
#pragma unroll
  for (int i = 0; i < 4; ++i) {
    aoff[i] = (wm * 64 + i * 16 + l16) * 64;
    boff[i] = (wn * 64 + i * 16 + l16) * 64;
  }

  f32x4 acc[4][4] = {};

  for (int kb = 0; kb < KDIM; kb += 64) {
    __syncthreads();  // previous compute done before LDS overwrite
#pragma unroll
    for (int j = 0; j < 4; ++j) {
      load_lds16(ga[j] + kb, sa[j]);
      load_lds16(gb[j] + kb, sb[j]);
    }
    __syncthreads();  // drains vmcnt -> staged data visible
#pragma unroll
    for (int kk = 0; kk < 2; ++kk) {
      const int ko = koff0 ^ (kk * 32);
      bf16x8 af[4], bfr[4];
#pragma unroll
      for (int i = 0; i < 4; ++i) {
        af[i]  = *(const bf16x8*)((const u16*)As + aoff[i] + ko);
        bfr[i] = *(const bf16x8*)((const u16*)Bs + boff[i] + ko);
      }
#pragma unroll
      for (int i = 0; i < 4; ++i) {
#pragma unroll
        for (int j = 0; j < 4; ++j) {
          acc[i][j] = __builtin_amdgcn_mfma_f32_16x16x32_bf16(af[i], bfr[j], acc[i][j], 0, 0, 0);
        }
      }
    }
  }

  // Epilogue: C/D layout col = lane&15, row = quad*4 + reg
  float bv[4];
#pragma unroll
  for (int j = 0; j < 4; ++j) bv[j] = bias[colBase + wn * 64 + j * 16 + l16];

#pragma unroll
  for (int i = 0; i < 4; ++i) {
#pragma unroll
    for (int r = 0; r < 4; ++r) {
      int grow = rowBase + wm * 64 + i * 16 + quad * 4 + r;
      float* crow = C + (size_t)grow * NDIM + colBase + wn * 64 + l16;
#pragma unroll
      for (int j = 0; j < 4; ++j) {
        crow[j * 16] = acc[i][j][r] + bv[j];
      }
    }
  }
}

// ---------------------------------------------------------------- launch ----

extern "C" void kernel_launch(void* const* d_in, const int* in_sizes, int n_in,
                              void* d_out, int out_size, void* d_ws, size_t ws_size,
                              hipStream_t stream) {
  const float* x    = (const float*)d_in[0];
  const float* w    = (const float*)d_in[1];
  const float* bias = (const float*)d_in[2];
  float* out = (float*)d_out;

  // workspace: Xb bf16 [MDIM*KDIM] then Qb bf16 [NDIM*KDIM]  (= 100.7 MB)
  u16* xb = (u16*)d_ws;
  u16* qb = xb + (size_t)MDIM * KDIM;

  cvt_kernel<<<(unsigned)(XBLOCKS + WBLOCKS), 256, 0, stream>>>(x, xb, w, qb);

  dim3 grid(NDIM / 128, MDIM / 128);
  gemm_tern_kernel<<<grid, 256, 0, stream>>>(xb, qb, bias, out);
}